// Round 2
// baseline (621.838 us; speedup 1.0000x reference)
//
#include <hip/hip_runtime.h>
#include <math.h>

#define EPS 1e-5f

// ---------- helpers ----------
__device__ __forceinline__ float waveReduceSum(float v) {
#pragma unroll
    for (int off = 32; off > 0; off >>= 1) v += __shfl_xor(v, off, 64);
    return v;
}

// ---------- K2: e1 conv (1->256,k3) + bn2 + relu (recomputed per block) + e2 conv (256->128,k3) + bn3 stats ----------
__global__ __launch_bounds__(128) void k2_enc12(const float* __restrict__ x,
                                                const float* __restrict__ w1,
                                                const float* __restrict__ b1,
                                                const float* __restrict__ g2,
                                                const float* __restrict__ bb2,
                                                const float* __restrict__ w2,
                                                const float* __restrict__ b2,
                                                float* __restrict__ h2,
                                                float* __restrict__ s3, float* __restrict__ q3) {
    __shared__ float xn[768];   // normalized+relu'd e1 output, taps for this p
    __shared__ float xs[33];
    int p = blockIdx.x;       // 0..28
    int t = threadIdx.x;      // 0..127
    if (t < 33) xs[t] = x[t];
    __syncthreads();
    for (int c = t; c < 256; c += 128) {
        float w0 = w1[c * 3], wa = w1[c * 3 + 1], wb = w1[c * 3 + 2], bias = b1[c];
        float s = 0.f, q = 0.f;
#pragma unroll
        for (int pp = 0; pp < 31; pp++) {
            float v = xs[pp] * w0 + xs[pp + 1] * wa + xs[pp + 2] * wb + bias;
            s += v; q += v * v;
        }
        float mean = s / 31.f;
        float var = q / 31.f - mean * mean;
        float sc = g2[c] * rsqrtf(var + EPS);
        float sh = bb2[c] - mean * sc;
#pragma unroll
        for (int k = 0; k < 3; k++) {
            float v = xs[p + k] * w0 + xs[p + k + 1] * wa + xs[p + k + 2] * wb + bias;
            v = v * sc + sh;
            xn[c * 3 + k] = v > 0.f ? v : 0.f;
        }
    }
    __syncthreads();
    float acc = b2[t];
    const float* wr = w2 + t * 768;
#pragma unroll 8
    for (int i = 0; i < 768; i++) acc += xn[i] * wr[i];
    h2[t * 29 + p] = acc;
    atomicAdd(&s3[t], acc);
    atomicAdd(&q3[t], acc * acc);
}

// ---------- K3: bn3+relu + e3 conv (128->64,k3) + bn4 stats (on relu(h3)) ----------
__global__ __launch_bounds__(64) void k3_enc3(const float* __restrict__ h2,
                                              const float* __restrict__ g, const float* __restrict__ bb,
                                              const float* __restrict__ s, const float* __restrict__ q,
                                              const float* __restrict__ w, const float* __restrict__ b3,
                                              float* __restrict__ h3,
                                              float* __restrict__ s4, float* __restrict__ q4) {
    __shared__ float xn[384];
    __shared__ float sc[128], sh[128];
    int p = blockIdx.x;   // 0..26
    int t = threadIdx.x;  // oc 0..63
    for (int ic = t; ic < 128; ic += 64) {
        float mean = s[ic] / 29.f;
        float var = q[ic] / 29.f - mean * mean;
        float scale = g[ic] / sqrtf(var + EPS);
        sc[ic] = scale; sh[ic] = bb[ic] - mean * scale;
    }
    __syncthreads();
    for (int i = t; i < 384; i += 64) {
        int ic = i / 3, k = i - ic * 3;
        float v = h2[ic * 29 + p + k] * sc[ic] + sh[ic];
        xn[i] = v > 0.f ? v : 0.f;
    }
    __syncthreads();
    float acc = b3[t];
    const float* wr = w + t * 384;
#pragma unroll 8
    for (int i = 0; i < 384; i++) acc += xn[i] * wr[i];
    h3[t * 27 + p] = acc;
    float r = acc > 0.f ? acc : 0.f;
    atomicAdd(&s4[t], r);
    atomicAdd(&q4[t], r * r);
}

// ---------- K4: bn4(on relu(h3)) + e4 conv (64->32,k3) -> h800 ----------
__global__ __launch_bounds__(64) void k4_enc4(const float* __restrict__ h3,
                                              const float* __restrict__ g, const float* __restrict__ bb,
                                              const float* __restrict__ s, const float* __restrict__ q,
                                              const float* __restrict__ w, const float* __restrict__ b4,
                                              float* __restrict__ h800) {
    __shared__ float sc[64], sh[64];
    int t = threadIdx.x;
    int idx = blockIdx.x * 64 + t;
    {
        float mean = s[t] / 27.f;
        float var = q[t] / 27.f - mean * mean;
        float scale = g[t] / sqrtf(var + EPS);
        sc[t] = scale; sh[t] = bb[t] - mean * scale;
    }
    __syncthreads();
    if (idx >= 800) return;
    int oc = idx / 25, p = idx - oc * 25;
    float acc = b4[oc];
    const float* wr = w + oc * 192;
    for (int ic = 0; ic < 64; ic++) {
#pragma unroll
        for (int k = 0; k < 3; k++) {
            float hv = h3[ic * 27 + p + k];
            hv = hv > 0.f ? hv : 0.f;
            acc += (hv * sc[ic] + sh[ic]) * wr[ic * 3 + k];
        }
    }
    h800[idx] = acc;  // idx == oc*25+p, matches reshape order
}

// ---------- K5: z = efc_w @ h800 + efc_b  (32768 rows x 800) ----------
__global__ __launch_bounds__(256) void k5_gemv1(const float* __restrict__ w,
                                                const float* __restrict__ h,
                                                const float* __restrict__ b,
                                                float* __restrict__ z) {
    int wave = threadIdx.x >> 6;
    int lane = threadIdx.x & 63;
    int row = blockIdx.x * 4 + wave;
    const float4* wr = (const float4*)(w + (size_t)row * 800);
    const float4* hv = (const float4*)h;
    float acc = 0.f;
#pragma unroll
    for (int t = 0; t < 3; t++) {
        float4 a = wr[lane + 64 * t];
        float4 c = hv[lane + 64 * t];
        acc += a.x * c.x + a.y * c.y + a.z * c.z + a.w * c.w;
    }
    if (lane < 8) {
        float4 a = wr[192 + lane];
        float4 c = hv[192 + lane];
        acc += a.x * c.x + a.y * c.y + a.z * c.z + a.w * c.w;
    }
    acc = waveReduceSum(acc);
    if (lane == 0) z[row] = acc + b[row];
}

// ---------- K67: Af = dot(X,Y)/(dot(X,X)+lam); powers[i]=Af^i (binary exp) ----------
__global__ __launch_bounds__(1024) void k67_afpow(const float* __restrict__ z, float* __restrict__ pw) {
    int t = threadIdx.x;
    float xy = 0.f, xx = 0.f;
    for (int i = t; i < 32767; i += 1024) {
        float a = z[i];
        xy += a * z[i + 1];
        xx += a * a;
    }
    xy = waveReduceSum(xy);
    xx = waveReduceSum(xx);
    __shared__ float sx[16], sy[16];
    __shared__ float afs;
    int wv = t >> 6, ln = t & 63;
    if (ln == 0) { sy[wv] = xy; sx[wv] = xx; }
    __syncthreads();
    if (t == 0) {
        float SY = 0.f, SX = 0.f;
        for (int i = 0; i < 16; i++) { SY += sy[i]; SX += sx[i]; }
        afs = SY / (SX + 0.01f);
    }
    __syncthreads();
    float base0 = afs;
    for (int i = t; i < 32767; i += 1024) {
        float r = 1.f, base = base0;
        int e = i;
        while (e) {
            if (e & 1) r *= base;
            base *= base;
            e >>= 1;
        }
        pw[i] = r;
    }
}

// ---------- K8: d(2x800) = out2 @ dfc_w.T + dfc_b, + dbn4 stats (float4 on dfc_w) ----------
__global__ __launch_bounds__(256) void k8_gemv2(const float* __restrict__ w,
                                                const float* __restrict__ z,
                                                const float* __restrict__ pw,
                                                const float* __restrict__ b,
                                                float* __restrict__ d,
                                                float* __restrict__ s, float* __restrict__ q) {
    int j = blockIdx.x;  // 0..799
    int t = threadIdx.x;
    const float* wr = w + (size_t)j * 32767;
    // row byte offset mod 16 = (12*j) mod 16 -> head = j%4 scalar elems aligns to 16B
    int head = j & 3;
    float a0 = 0.f, a1 = 0.f;
    if (t < head) { float wv = wr[t]; a0 += z[t] * wv; a1 += pw[t] * wv; }
    int n4 = (32767 - head) >> 2;           // 8191 always
    const float4* wv4 = (const float4*)(wr + head);
    for (int v = t; v < n4; v += 256) {
        float4 a = wv4[v];
        int i = head + 4 * v;
        a0 += z[i] * a.x + z[i + 1] * a.y + z[i + 2] * a.z + z[i + 3] * a.w;
        a1 += pw[i] * a.x + pw[i + 1] * a.y + pw[i + 2] * a.z + pw[i + 3] * a.w;
    }
    int tail = (32767 - head) & 3;
    int tstart = head + 4 * n4;
    if (t < tail) { int i = tstart + t; float wv = wr[i]; a0 += z[i] * wv; a1 += pw[i] * wv; }

    a0 = waveReduceSum(a0);
    a1 = waveReduceSum(a1);
    __shared__ float r0[4], r1[4];
    int wave = t >> 6, lane = t & 63;
    if (lane == 0) { r0[wave] = a0; r1[wave] = a1; }
    __syncthreads();
    if (t == 0) {
        float d0 = r0[0] + r0[1] + r0[2] + r0[3] + b[j];
        float d1 = z[0] * (r1[0] + r1[1] + r1[2] + r1[3]) + b[j];
        d[j] = d0;
        d[800 + j] = d1;
        int c0 = j / 50, c1 = 16 + j / 50;
        atomicAdd(&s[c0], d0); atomicAdd(&q[c0], d0 * d0);
        atomicAdd(&s[c1], d1); atomicAdd(&q[c1], d1 * d1);
    }
}

// ---------- K9: dbn4 + relu + convT d4 (32->64,k5) + dbn3 stats (on relu) ----------
__global__ __launch_bounds__(64) void k9_dec4(const float* __restrict__ dvec,
                                              const float* __restrict__ g, const float* __restrict__ bb,
                                              const float* __restrict__ s, const float* __restrict__ q,
                                              const float* __restrict__ w, const float* __restrict__ b4,
                                              float* __restrict__ h4,
                                              float* __restrict__ s3, float* __restrict__ q3) {
    __shared__ float xn[1600];
    __shared__ float sc[32], sh[32];
    int p = blockIdx.x;   // 0..53
    int t = threadIdx.x;  // oc 0..63
    if (t < 32) {
        float mean = s[t] / 50.f;
        float var = q[t] / 50.f - mean * mean;
        float scale = g[t] / sqrtf(var + EPS);
        sc[t] = scale; sh[t] = bb[t] - mean * scale;
    }
    __syncthreads();
    for (int i = t; i < 1600; i += 64) {
        int ic = i / 50;
        float v = dvec[i] * sc[ic] + sh[ic];
        xn[i] = v > 0.f ? v : 0.f;  // bn then relu
    }
    __syncthreads();
    float acc = b4[t];
    for (int ic = 0; ic < 32; ic++) {
        const float* wr = w + ic * 320 + t * 5;
#pragma unroll
        for (int k = 0; k < 5; k++) {
            int m = p - 4 + k;
            if (m >= 0 && m < 50) acc += xn[ic * 50 + m] * wr[4 - k];
        }
    }
    h4[t * 54 + p] = acc;
    float r = acc > 0.f ? acc : 0.f;
    atomicAdd(&s3[t], r);
    atomicAdd(&q3[t], r * r);
}

// ---------- K10: dbn3(on relu) + convT d3 (64->128,k5) + dbn2 stats (on relu) ----------
__global__ __launch_bounds__(128) void k10_dec3(const float* __restrict__ h4,
                                                const float* __restrict__ g, const float* __restrict__ bb,
                                                const float* __restrict__ s, const float* __restrict__ q,
                                                const float* __restrict__ w, const float* __restrict__ b3,
                                                float* __restrict__ h5,
                                                float* __restrict__ s2, float* __restrict__ q2) {
    __shared__ float xn[3456];
    __shared__ float sc[64], sh[64];
    int p = blockIdx.x;   // 0..57
    int t = threadIdx.x;  // oc 0..127
    if (t < 64) {
        float mean = s[t] / 54.f;
        float var = q[t] / 54.f - mean * mean;
        float scale = g[t] / sqrtf(var + EPS);
        sc[t] = scale; sh[t] = bb[t] - mean * scale;
    }
    __syncthreads();
    for (int i = t; i < 3456; i += 128) {
        int ic = i / 54;
        float hv = h4[i];
        hv = hv > 0.f ? hv : 0.f;      // relu then bn
        xn[i] = hv * sc[ic] + sh[ic];
    }
    __syncthreads();
    float acc = b3[t];
    for (int ic = 0; ic < 64; ic++) {
        const float* wr = w + ic * 640 + t * 5;
#pragma unroll
        for (int k = 0; k < 5; k++) {
            int m = p - 4 + k;
            if (m >= 0 && m < 54) acc += xn[ic * 54 + m] * wr[4 - k];
        }
    }
    h5[t * 58 + p] = acc;
    float r = acc > 0.f ? acc : 0.f;
    atomicAdd(&s2[t], r);
    atomicAdd(&q2[t], r * r);
}

// ---------- K11: dbn2(on relu) + convT d2 (128->256,k5) + dbn1 stats (raw) ----------
__global__ __launch_bounds__(256) void k11_dec2(const float* __restrict__ h5,
                                                const float* __restrict__ g, const float* __restrict__ bb,
                                                const float* __restrict__ s, const float* __restrict__ q,
                                                const float* __restrict__ w, const float* __restrict__ b2,
                                                float* __restrict__ h6,
                                                float* __restrict__ s1, float* __restrict__ q1) {
    __shared__ float xn[7424];
    __shared__ float sc[128], sh[128];
    int p = blockIdx.x;   // 0..61
    int t = threadIdx.x;  // oc 0..255
    if (t < 128) {
        float mean = s[t] / 58.f;
        float var = q[t] / 58.f - mean * mean;
        float scale = g[t] / sqrtf(var + EPS);
        sc[t] = scale; sh[t] = bb[t] - mean * scale;
    }
    __syncthreads();
    for (int i = t; i < 7424; i += 256) {
        int ic = i / 58;
        float hv = h5[i];
        hv = hv > 0.f ? hv : 0.f;      // relu then bn
        xn[i] = hv * sc[ic] + sh[ic];
    }
    __syncthreads();
    float acc = b2[t];
    for (int ic = 0; ic < 128; ic++) {
        const float* wr = w + ic * 1280 + t * 5;
#pragma unroll
        for (int k = 0; k < 5; k++) {
            int m = p - 4 + k;
            if (m >= 0 && m < 58) acc += xn[ic * 58 + m] * wr[4 - k];
        }
    }
    h6[t * 62 + p] = acc;
    atomicAdd(&s1[t], acc);           // dbn1 stats on raw h6
    atomicAdd(&q1[t], acc * acc);
}

// ---------- K12: dbn1 + relu + convT d1 (256->1,k3) -> out(64) ----------
__global__ __launch_bounds__(64) void k12_dec1(const float* __restrict__ h6,
                                               const float* __restrict__ g, const float* __restrict__ bb,
                                               const float* __restrict__ s, const float* __restrict__ q,
                                               const float* __restrict__ w, const float* __restrict__ b1,
                                               float* __restrict__ out) {
    __shared__ float sc[256], sh[256];
    int t = threadIdx.x;  // p 0..63
    for (int ic = t; ic < 256; ic += 64) {
        float mean = s[ic] / 62.f;
        float var = q[ic] / 62.f - mean * mean;
        float scale = g[ic] / sqrtf(var + EPS);
        sc[ic] = scale; sh[ic] = bb[ic] - mean * scale;
    }
    __syncthreads();
    int p = t;
    float acc = b1[0];
    for (int ic = 0; ic < 256; ic++) {
#pragma unroll
        for (int k = 0; k < 3; k++) {
            int m = p - 2 + k;
            if (m >= 0 && m < 62) {
                float v = sc[ic] * h6[ic * 62 + m] + sh[ic];
                v = v > 0.f ? v : 0.f;  // bn then relu
                acc += v * w[ic * 3 + 2 - k];
            }
        }
    }
    out[p] = acc;
}

// ---------- launcher ----------
extern "C" void kernel_launch(void* const* d_in, const int* in_sizes, int n_in,
                              void* d_out, int out_size, void* d_ws, size_t ws_size,
                              hipStream_t stream) {
    const float* x      = (const float*)d_in[0];
    const float* e1_w   = (const float*)d_in[1];
    const float* e1_b   = (const float*)d_in[2];
    const float* bn2_g  = (const float*)d_in[3];
    const float* bn2_b  = (const float*)d_in[4];
    const float* e2_w   = (const float*)d_in[5];
    const float* e2_b   = (const float*)d_in[6];
    const float* bn3_g  = (const float*)d_in[7];
    const float* bn3_b  = (const float*)d_in[8];
    const float* e3_w   = (const float*)d_in[9];
    const float* e3_b   = (const float*)d_in[10];
    const float* bn4_g  = (const float*)d_in[11];
    const float* bn4_b  = (const float*)d_in[12];
    const float* e4_w   = (const float*)d_in[13];
    const float* e4_b   = (const float*)d_in[14];
    const float* efc_w  = (const float*)d_in[15];
    const float* efc_b  = (const float*)d_in[16];
    const float* dfc_w  = (const float*)d_in[17];
    const float* dfc_b  = (const float*)d_in[18];
    const float* dbn4_g = (const float*)d_in[19];
    const float* dbn4_b = (const float*)d_in[20];
    const float* d4_w   = (const float*)d_in[21];
    const float* d4_b   = (const float*)d_in[22];
    const float* dbn3_g = (const float*)d_in[23];
    const float* dbn3_b = (const float*)d_in[24];
    const float* d3_w   = (const float*)d_in[25];
    const float* d3_b   = (const float*)d_in[26];
    const float* dbn2_g = (const float*)d_in[27];
    const float* dbn2_b = (const float*)d_in[28];
    const float* d2_w   = (const float*)d_in[29];
    const float* d2_b   = (const float*)d_in[30];
    const float* dbn1_g = (const float*)d_in[31];
    const float* dbn1_b = (const float*)d_in[32];
    const float* d1_w   = (const float*)d_in[33];
    const float* d1_b   = (const float*)d_in[34];
    float* out = (float*)d_out;

    float* W = (float*)d_ws;
    float* bn3s  = W + 0;    float* bn3q  = W + 128;
    float* bn4s  = W + 256;  float* bn4q  = W + 320;
    float* dbn4s = W + 384;  float* dbn4q = W + 416;
    float* dbn3s = W + 448;  float* dbn3q = W + 512;
    float* dbn2s = W + 576;  float* dbn2q = W + 704;
    float* dbn1s = W + 832;  float* dbn1q = W + 1088;   // stats end at 1344
    float* h2    = W + 1344;   // 128*29 = 3712
    float* h3    = W + 5056;   // 64*27  = 1728
    float* h800  = W + 6784;   // 800
    float* z     = W + 7584;   // 32768 (16B-aligned: 7584*4 % 16 == 0)
    float* pw    = W + 40352;  // 32768
    float* dvec  = W + 73120;  // 1600
    float* h4    = W + 74720;  // 64*54  = 3456
    float* h5    = W + 78176;  // 128*58 = 7424
    float* h6    = W + 85600;  // 256*62 = 15872 -> total 101472 floats (~406 KB)

    // zero the BN-stats accumulators
    hipMemsetAsync(d_ws, 0, 1344 * sizeof(float), stream);

    k2_enc12<<<29, 128, 0, stream>>>(x, e1_w, e1_b, bn2_g, bn2_b, e2_w, e2_b, h2, bn3s, bn3q);
    k3_enc3<<<27, 64, 0, stream>>>(h2, bn3_g, bn3_b, bn3s, bn3q, e3_w, e3_b, h3, bn4s, bn4q);
    k4_enc4<<<13, 64, 0, stream>>>(h3, bn4_g, bn4_b, bn4s, bn4q, e4_w, e4_b, h800);
    k5_gemv1<<<8192, 256, 0, stream>>>(efc_w, h800, efc_b, z);
    k67_afpow<<<1, 1024, 0, stream>>>(z, pw);
    k8_gemv2<<<800, 256, 0, stream>>>(dfc_w, z, pw, dfc_b, dvec, dbn4s, dbn4q);
    k9_dec4<<<54, 64, 0, stream>>>(dvec, dbn4_g, dbn4_b, dbn4s, dbn4q, d4_w, d4_b, h4, dbn3s, dbn3q);
    k10_dec3<<<58, 128, 0, stream>>>(h4, dbn3_g, dbn3_b, dbn3s, dbn3q, d3_w, d3_b, h5, dbn2s, dbn2q);
    k11_dec2<<<62, 256, 0, stream>>>(h5, dbn2_g, dbn2_b, dbn2s, dbn2q, d2_w, d2_b, h6, dbn1s, dbn1q);
    k12_dec1<<<1, 64, 0, stream>>>(h6, dbn1_g, dbn1_b, dbn1s, dbn1q, d1_w, d1_b, out);
}

// Round 3
// 543.515 us; speedup vs baseline: 1.1441x; 1.1441x over previous
//
#include <hip/hip_runtime.h>
#include <math.h>

#define EPS 1e-5f

// ---------- helpers ----------
__device__ __forceinline__ float waveReduceSum(float v) {
#pragma unroll
    for (int off = 32; off > 0; off >>= 1) v += __shfl_xor(v, off, 64);
    return v;
}

// ---------- K2: e1 conv (1->256,k3)+bn2+relu (recomputed per block, into LDS) + e2 conv (256->128,k3) + bn3 stats ----------
// 256 threads = 2 p-positions x 128 oc. grid 15 (p 0..28, guard).
__global__ __launch_bounds__(256) void k2_enc12(const float* __restrict__ x,
                                                const float* __restrict__ w1,
                                                const float* __restrict__ b1,
                                                const float* __restrict__ g2,
                                                const float* __restrict__ bb2,
                                                const float* __restrict__ w2,
                                                const float* __restrict__ b2,
                                                float* __restrict__ h2,
                                                float* __restrict__ s3, float* __restrict__ q3) {
    __shared__ float xs[33];
    __shared__ float e1[256 * 32];   // padded rows
    int t = threadIdx.x;
    if (t < 33) xs[t] = x[t];
    __syncthreads();
    {   // thread t computes channel t of e1 + bn2 + relu
        int c = t;
        float w0 = w1[c * 3], wa = w1[c * 3 + 1], wb = w1[c * 3 + 2], bias = b1[c];
        float vals[31];
        float s = 0.f, q = 0.f;
#pragma unroll
        for (int pp = 0; pp < 31; pp++) {
            float v = xs[pp] * w0 + xs[pp + 1] * wa + xs[pp + 2] * wb + bias;
            vals[pp] = v; s += v; q += v * v;
        }
        float mean = s / 31.f;
        float var = q / 31.f - mean * mean;
        float sc = g2[c] * rsqrtf(var + EPS);
        float sh = bb2[c] - mean * sc;
#pragma unroll
        for (int pp = 0; pp < 31; pp++) {
            float v = vals[pp] * sc + sh;
            e1[c * 32 + pp] = v > 0.f ? v : 0.f;
        }
    }
    __syncthreads();
    int oc = t & 127, ps = t >> 7;
    int p = blockIdx.x * 2 + ps;
    if (p >= 29) return;
    const float4* wr4 = (const float4*)(w2 + oc * 768);
    const float* ep = e1 + p;
    float acc0 = b2[oc], acc1 = 0.f;
#pragma unroll 4
    for (int m = 0; m < 64; m++) {   // 12 weights = 4 input channels per iter
        float4 a = wr4[3 * m], bq = wr4[3 * m + 1], c = wr4[3 * m + 2];
        const float* e0 = ep + (4 * m) * 32;
        acc0 += e0[0] * a.x + e0[1] * a.y + e0[2] * a.z;
        acc1 += e0[32] * a.w + e0[33] * bq.x + e0[34] * bq.y;
        acc0 += e0[64] * bq.z + e0[65] * bq.w + e0[66] * c.x;
        acc1 += e0[96] * c.y + e0[97] * c.z + e0[98] * c.w;
    }
    float acc = acc0 + acc1;
    h2[oc * 29 + p] = acc;
    atomicAdd(&s3[oc], acc);
    atomicAdd(&q3[oc], acc * acc);
}

// ---------- K3: bn3+relu + e3 conv (128->64,k3) + bn4 stats (on relu(h3)) ----------
// 256 threads = 4 p x 64 oc. grid 7 (p 0..26, guard).
__global__ __launch_bounds__(256) void k3_enc3(const float* __restrict__ h2,
                                               const float* __restrict__ g, const float* __restrict__ bb,
                                               const float* __restrict__ s, const float* __restrict__ q,
                                               const float* __restrict__ w, const float* __restrict__ b3,
                                               float* __restrict__ h3,
                                               float* __restrict__ s4, float* __restrict__ q4) {
    __shared__ float xn[128 * 30];
    __shared__ float sc[128], sh[128];
    int t = threadIdx.x;
    if (t < 128) {
        float mean = s[t] / 29.f;
        float var = q[t] / 29.f - mean * mean;
        float scale = g[t] * rsqrtf(var + EPS);
        sc[t] = scale; sh[t] = bb[t] - mean * scale;
    }
    __syncthreads();
    for (int i = t; i < 3712; i += 256) {
        int ic = i / 29, pos = i - ic * 29;
        float v = h2[i] * sc[ic] + sh[ic];
        xn[ic * 30 + pos] = v > 0.f ? v : 0.f;
    }
    __syncthreads();
    int oc = t & 63, ps = t >> 6;
    int p = blockIdx.x * 4 + ps;
    if (p >= 27) return;
    const float4* wr4 = (const float4*)(w + oc * 384);
    const float* xp = xn + p;
    float acc0 = b3[oc], acc1 = 0.f;
#pragma unroll 4
    for (int m = 0; m < 32; m++) {
        float4 a = wr4[3 * m], bq = wr4[3 * m + 1], c = wr4[3 * m + 2];
        const float* x0 = xp + (4 * m) * 30;
        acc0 += x0[0] * a.x + x0[1] * a.y + x0[2] * a.z;
        acc1 += x0[30] * a.w + x0[31] * bq.x + x0[32] * bq.y;
        acc0 += x0[60] * bq.z + x0[61] * bq.w + x0[62] * c.x;
        acc1 += x0[90] * c.y + x0[91] * c.z + x0[92] * c.w;
    }
    float acc = acc0 + acc1;
    h3[oc * 27 + p] = acc;
    float r = acc > 0.f ? acc : 0.f;
    atomicAdd(&s4[oc], r);
    atomicAdd(&q4[oc], r * r);
}

// ---------- K4: bn4(on relu(h3)) + e4 conv (64->32,k3) -> h800, weights + input in LDS ----------
// 256 threads, grid 4 (800 outputs, guard).
__global__ __launch_bounds__(256) void k4_enc4(const float* __restrict__ h3,
                                               const float* __restrict__ g, const float* __restrict__ bb,
                                               const float* __restrict__ s, const float* __restrict__ q,
                                               const float* __restrict__ w, const float* __restrict__ b4,
                                               float* __restrict__ h800) {
    __shared__ float xn[64 * 28];
    __shared__ float wl[6144];
    __shared__ float sc[64], sh[64];
    int t = threadIdx.x;
    if (t < 64) {
        float mean = s[t] / 27.f;
        float var = q[t] / 27.f - mean * mean;
        float scale = g[t] * rsqrtf(var + EPS);
        sc[t] = scale; sh[t] = bb[t] - mean * scale;
    }
    __syncthreads();
    for (int i = t; i < 1728; i += 256) {
        int ic = i / 27, pos = i - ic * 27;
        float hv = h3[i];
        hv = hv > 0.f ? hv : 0.f;           // relu then bn
        xn[ic * 28 + pos] = hv * sc[ic] + sh[ic];
    }
    for (int i = t; i < 6144; i += 256) wl[i] = w[i];
    __syncthreads();
    int idx = blockIdx.x * 256 + t;
    if (idx >= 800) return;
    int oc = idx / 25, p = idx - oc * 25;
    const float* wr = wl + oc * 192;
    const float* xp = xn + p;
    float acc0 = b4[oc], acc1 = 0.f;
#pragma unroll 8
    for (int ic = 0; ic < 64; ic += 2) {
        const float* x0 = xp + ic * 28;
        acc0 += x0[0] * wr[ic * 3] + x0[1] * wr[ic * 3 + 1] + x0[2] * wr[ic * 3 + 2];
        acc1 += x0[28] * wr[ic * 3 + 3] + x0[29] * wr[ic * 3 + 4] + x0[30] * wr[ic * 3 + 5];
    }
    h800[idx] = acc0 + acc1;   // idx == oc*25+p, matches reshape order
}

// ---------- K5: z = efc_w @ h800 + efc_b  (32768 rows x 800) ----------
__global__ __launch_bounds__(256) void k5_gemv1(const float* __restrict__ w,
                                                const float* __restrict__ h,
                                                const float* __restrict__ b,
                                                float* __restrict__ z) {
    int wave = threadIdx.x >> 6;
    int lane = threadIdx.x & 63;
    int row = blockIdx.x * 4 + wave;
    const float4* wr = (const float4*)(w + (size_t)row * 800);
    const float4* hv = (const float4*)h;
    float acc = 0.f;
#pragma unroll
    for (int t = 0; t < 3; t++) {
        float4 a = wr[lane + 64 * t];
        float4 c = hv[lane + 64 * t];
        acc += a.x * c.x + a.y * c.y + a.z * c.z + a.w * c.w;
    }
    if (lane < 8) {
        float4 a = wr[192 + lane];
        float4 c = hv[192 + lane];
        acc += a.x * c.x + a.y * c.y + a.z * c.z + a.w * c.w;
    }
    acc = waveReduceSum(acc);
    if (lane == 0) z[row] = acc + b[row];
}

// ---------- K67: Af = dot(X,Y)/(dot(X,X)+lam); powers[i]=Af^i (binary exp) ----------
__global__ __launch_bounds__(1024) void k67_afpow(const float* __restrict__ z, float* __restrict__ pw) {
    int t = threadIdx.x;
    float xy = 0.f, xx = 0.f;
    for (int i = t; i < 32767; i += 1024) {
        float a = z[i];
        xy += a * z[i + 1];
        xx += a * a;
    }
    xy = waveReduceSum(xy);
    xx = waveReduceSum(xx);
    __shared__ float sx[16], sy[16];
    __shared__ float afs;
    int wv = t >> 6, ln = t & 63;
    if (ln == 0) { sy[wv] = xy; sx[wv] = xx; }
    __syncthreads();
    if (t == 0) {
        float SY = 0.f, SX = 0.f;
        for (int i = 0; i < 16; i++) { SY += sy[i]; SX += sx[i]; }
        afs = SY / (SX + 0.01f);
    }
    __syncthreads();
    float base0 = afs;
    for (int i = t; i < 32767; i += 1024) {
        float r = 1.f, base = base0;
        int e = i;
        while (e) {
            if (e & 1) r *= base;
            base *= base;
            e >>= 1;
        }
        pw[i] = r;
    }
}

// ---------- K8: d(2x800) = out2 @ dfc_w.T + dfc_b, + dbn4 stats (float4 on dfc_w) ----------
__global__ __launch_bounds__(256) void k8_gemv2(const float* __restrict__ w,
                                                const float* __restrict__ z,
                                                const float* __restrict__ pw,
                                                const float* __restrict__ b,
                                                float* __restrict__ d,
                                                float* __restrict__ s, float* __restrict__ q) {
    int j = blockIdx.x;  // 0..799
    int t = threadIdx.x;
    const float* wr = w + (size_t)j * 32767;
    int head = j & 3;     // (12*j mod 16)/4 -> j%4 scalars align row to 16B
    float a0 = 0.f, a1 = 0.f;
    if (t < head) { float wv = wr[t]; a0 += z[t] * wv; a1 += pw[t] * wv; }
    int n4 = (32767 - head) >> 2;
    const float4* wv4 = (const float4*)(wr + head);
    for (int v = t; v < n4; v += 256) {
        float4 a = wv4[v];
        int i = head + 4 * v;
        a0 += z[i] * a.x + z[i + 1] * a.y + z[i + 2] * a.z + z[i + 3] * a.w;
        a1 += pw[i] * a.x + pw[i + 1] * a.y + pw[i + 2] * a.z + pw[i + 3] * a.w;
    }
    int tail = (32767 - head) & 3;
    int tstart = head + 4 * n4;
    if (t < tail) { int i = tstart + t; float wv = wr[i]; a0 += z[i] * wv; a1 += pw[i] * wv; }

    a0 = waveReduceSum(a0);
    a1 = waveReduceSum(a1);
    __shared__ float r0[4], r1[4];
    int wave = t >> 6, lane = t & 63;
    if (lane == 0) { r0[wave] = a0; r1[wave] = a1; }
    __syncthreads();
    if (t == 0) {
        float d0 = r0[0] + r0[1] + r0[2] + r0[3] + b[j];
        float d1 = z[0] * (r1[0] + r1[1] + r1[2] + r1[3]) + b[j];
        d[j] = d0;
        d[800 + j] = d1;
        int c0 = j / 50, c1 = 16 + j / 50;
        atomicAdd(&s[c0], d0); atomicAdd(&q[c0], d0 * d0);
        atomicAdd(&s[c1], d1); atomicAdd(&q[c1], d1 * d1);
    }
}

// ---------- K9: dbn4+relu + convT d4 (32->64,k5) + dbn3 stats (on relu). weights in LDS ----------
// 256 threads = 4 p x 64 oc, grid 14 (p 0..53, guard)
__global__ __launch_bounds__(256) void k9_dec4(const float* __restrict__ dvec,
                                               const float* __restrict__ g, const float* __restrict__ bb,
                                               const float* __restrict__ s, const float* __restrict__ q,
                                               const float* __restrict__ w, const float* __restrict__ b4,
                                               float* __restrict__ h4,
                                               float* __restrict__ s3, float* __restrict__ q3) {
    __shared__ float xn[1600];
    __shared__ float wl[10240];
    __shared__ float sc[32], sh[32];
    int t = threadIdx.x;
    if (t < 32) {
        float mean = s[t] / 50.f;
        float var = q[t] / 50.f - mean * mean;
        float scale = g[t] * rsqrtf(var + EPS);
        sc[t] = scale; sh[t] = bb[t] - mean * scale;
    }
    __syncthreads();
    for (int i = t; i < 1600; i += 256) {
        int ic = i / 50;
        float v = dvec[i] * sc[ic] + sh[ic];
        xn[i] = v > 0.f ? v : 0.f;  // bn then relu
    }
    for (int i = t; i < 10240; i += 256) wl[i] = w[i];
    __syncthreads();
    int oc = t & 63, ps = t >> 6;
    int p = blockIdx.x * 4 + ps;
    if (p >= 54) return;
    float acc = b4[oc];
    for (int ic = 0; ic < 32; ic++) {
        const float* wr = wl + ic * 320 + oc * 5;
        const float* x0 = xn + ic * 50;
#pragma unroll
        for (int k = 0; k < 5; k++) {
            int m = p - 4 + k;
            if (m >= 0 && m < 50) acc += x0[m] * wr[4 - k];
        }
    }
    h4[oc * 54 + p] = acc;
    float r = acc > 0.f ? acc : 0.f;
    atomicAdd(&s3[oc], r);
    atomicAdd(&q3[oc], r * r);
}

// ---------- K10: dbn3(on relu) + convT d3 (64->128,k5) + dbn2 stats (on relu) ----------
// 256 threads = 2 p x 128 oc, grid 29 (58 exact)
__global__ __launch_bounds__(256) void k10_dec3(const float* __restrict__ h4,
                                                const float* __restrict__ g, const float* __restrict__ bb,
                                                const float* __restrict__ s, const float* __restrict__ q,
                                                const float* __restrict__ w, const float* __restrict__ b3,
                                                float* __restrict__ h5,
                                                float* __restrict__ s2, float* __restrict__ q2) {
    __shared__ float xn[3456];
    __shared__ float sc[64], sh[64];
    int t = threadIdx.x;
    if (t < 64) {
        float mean = s[t] / 54.f;
        float var = q[t] / 54.f - mean * mean;
        float scale = g[t] * rsqrtf(var + EPS);
        sc[t] = scale; sh[t] = bb[t] - mean * scale;
    }
    __syncthreads();
    for (int i = t; i < 3456; i += 256) {
        int ic = i / 54;
        float hv = h4[i];
        hv = hv > 0.f ? hv : 0.f;           // relu then bn
        xn[i] = hv * sc[ic] + sh[ic];
    }
    __syncthreads();
    int oc = t & 127, ps = t >> 7;
    int p = blockIdx.x * 2 + ps;
    float acc0 = b3[oc], acc1 = 0.f;
    for (int ic = 0; ic < 64; ic += 2) {
        const float* wr = w + ic * 640 + oc * 5;
        const float* x0 = xn + ic * 54;
#pragma unroll
        for (int k = 0; k < 5; k++) {
            int m = p - 4 + k;
            if (m >= 0 && m < 54) acc0 += x0[m] * wr[4 - k];
        }
        const float* wr1 = wr + 640;
        const float* x1 = x0 + 54;
#pragma unroll
        for (int k = 0; k < 5; k++) {
            int m = p - 4 + k;
            if (m >= 0 && m < 54) acc1 += x1[m] * wr1[4 - k];
        }
    }
    float acc = acc0 + acc1;
    h5[oc * 58 + p] = acc;
    float r = acc > 0.f ? acc : 0.f;
    atomicAdd(&s2[oc], r);
    atomicAdd(&q2[oc], r * r);
}

// ---------- K11: dbn2(on relu) + convT d2 (128->256,k5) + dbn1 stats (raw) ----------
// 512 threads = 2 p x 256 oc, grid 31 (62 exact)
__global__ __launch_bounds__(512) void k11_dec2(const float* __restrict__ h5,
                                                const float* __restrict__ g, const float* __restrict__ bb,
                                                const float* __restrict__ s, const float* __restrict__ q,
                                                const float* __restrict__ w, const float* __restrict__ b2,
                                                float* __restrict__ h6,
                                                float* __restrict__ s1, float* __restrict__ q1) {
    __shared__ float xn[7424];
    __shared__ float sc[128], sh[128];
    int t = threadIdx.x;
    if (t < 128) {
        float mean = s[t] / 58.f;
        float var = q[t] / 58.f - mean * mean;
        float scale = g[t] * rsqrtf(var + EPS);
        sc[t] = scale; sh[t] = bb[t] - mean * scale;
    }
    __syncthreads();
    for (int i = t; i < 7424; i += 512) {
        int ic = i / 58;
        float hv = h5[i];
        hv = hv > 0.f ? hv : 0.f;           // relu then bn
        xn[i] = hv * sc[ic] + sh[ic];
    }
    __syncthreads();
    int oc = t & 255, ps = t >> 8;
    int p = blockIdx.x * 2 + ps;
    float acc0 = b2[oc], acc1 = 0.f;
    for (int ic = 0; ic < 128; ic += 2) {
        const float* wr = w + ic * 1280 + oc * 5;
        const float* x0 = xn + ic * 58;
#pragma unroll
        for (int k = 0; k < 5; k++) {
            int m = p - 4 + k;
            if (m >= 0 && m < 58) acc0 += x0[m] * wr[4 - k];
        }
        const float* wr1 = wr + 1280;
        const float* x1 = x0 + 58;
#pragma unroll
        for (int k = 0; k < 5; k++) {
            int m = p - 4 + k;
            if (m >= 0 && m < 58) acc1 += x1[m] * wr1[4 - k];
        }
    }
    float acc = acc0 + acc1;
    h6[oc * 62 + p] = acc;
    atomicAdd(&s1[oc], acc);               // dbn1 stats on raw h6
    atomicAdd(&q1[oc], acc * acc);
}

// ---------- K12: dbn1 + relu + convT d1 (256->1,k3) -> out(64). 512 threads, 8-way split + LDS reduce ----------
__global__ __launch_bounds__(512) void k12_dec1(const float* __restrict__ h6,
                                                const float* __restrict__ g, const float* __restrict__ bb,
                                                const float* __restrict__ s, const float* __restrict__ q,
                                                const float* __restrict__ w, const float* __restrict__ b1,
                                                float* __restrict__ out) {
    __shared__ float scb[256], shb[256];
    __shared__ float wl[768];
    __shared__ float partial[8][64];
    int t = threadIdx.x;
    if (t < 256) {
        float mean = s[t] / 62.f;
        float var = q[t] / 62.f - mean * mean;
        float scale = g[t] * rsqrtf(var + EPS);
        scb[t] = scale; shb[t] = bb[t] - mean * scale;
    }
    for (int i = t; i < 768; i += 512) wl[i] = w[i];
    __syncthreads();
    int p = t & 63, grp = t >> 6;   // 8 groups x 32 ic
    float acc = 0.f;
    for (int ic = grp * 32; ic < grp * 32 + 32; ic++) {
        float scv = scb[ic], shv = shb[ic];
        const float* hrow = h6 + ic * 62;
        const float* wr = wl + ic * 3;
#pragma unroll
        for (int k = 0; k < 3; k++) {
            int m = p - 2 + k;
            if (m >= 0 && m < 62) {
                float v = hrow[m] * scv + shv;
                v = v > 0.f ? v : 0.f;      // bn then relu
                acc += v * wr[2 - k];
            }
        }
    }
    partial[grp][p] = acc;
    __syncthreads();
    if (t < 64) {
        float a = b1[0];
#pragma unroll
        for (int g2 = 0; g2 < 8; g2++) a += partial[g2][t];
        out[t] = a;
    }
}

// ---------- launcher ----------
extern "C" void kernel_launch(void* const* d_in, const int* in_sizes, int n_in,
                              void* d_out, int out_size, void* d_ws, size_t ws_size,
                              hipStream_t stream) {
    const float* x      = (const float*)d_in[0];
    const float* e1_w   = (const float*)d_in[1];
    const float* e1_b   = (const float*)d_in[2];
    const float* bn2_g  = (const float*)d_in[3];
    const float* bn2_b  = (const float*)d_in[4];
    const float* e2_w   = (const float*)d_in[5];
    const float* e2_b   = (const float*)d_in[6];
    const float* bn3_g  = (const float*)d_in[7];
    const float* bn3_b  = (const float*)d_in[8];
    const float* e3_w   = (const float*)d_in[9];
    const float* e3_b   = (const float*)d_in[10];
    const float* bn4_g  = (const float*)d_in[11];
    const float* bn4_b  = (const float*)d_in[12];
    const float* e4_w   = (const float*)d_in[13];
    const float* e4_b   = (const float*)d_in[14];
    const float* efc_w  = (const float*)d_in[15];
    const float* efc_b  = (const float*)d_in[16];
    const float* dfc_w  = (const float*)d_in[17];
    const float* dfc_b  = (const float*)d_in[18];
    const float* dbn4_g = (const float*)d_in[19];
    const float* dbn4_b = (const float*)d_in[20];
    const float* d4_w   = (const float*)d_in[21];
    const float* d4_b   = (const float*)d_in[22];
    const float* dbn3_g = (const float*)d_in[23];
    const float* dbn3_b = (const float*)d_in[24];
    const float* d3_w   = (const float*)d_in[25];
    const float* d3_b   = (const float*)d_in[26];
    const float* dbn2_g = (const float*)d_in[27];
    const float* dbn2_b = (const float*)d_in[28];
    const float* d2_w   = (const float*)d_in[29];
    const float* d2_b   = (const float*)d_in[30];
    const float* dbn1_g = (const float*)d_in[31];
    const float* dbn1_b = (const float*)d_in[32];
    const float* d1_w   = (const float*)d_in[33];
    const float* d1_b   = (const float*)d_in[34];
    float* out = (float*)d_out;

    float* W = (float*)d_ws;
    float* bn3s  = W + 0;    float* bn3q  = W + 128;
    float* bn4s  = W + 256;  float* bn4q  = W + 320;
    float* dbn4s = W + 384;  float* dbn4q = W + 416;
    float* dbn3s = W + 448;  float* dbn3q = W + 512;
    float* dbn2s = W + 576;  float* dbn2q = W + 704;
    float* dbn1s = W + 832;  float* dbn1q = W + 1088;   // stats end at 1344
    float* h2    = W + 1344;   // 128*29 = 3712
    float* h3    = W + 5056;   // 64*27  = 1728
    float* h800  = W + 6784;   // 800
    float* z     = W + 7584;   // 32768 (16B-aligned)
    float* pw    = W + 40352;  // 32768
    float* dvec  = W + 73120;  // 1600
    float* h4    = W + 74720;  // 64*54  = 3456
    float* h5    = W + 78176;  // 128*58 = 7424
    float* h6    = W + 85600;  // 256*62 = 15872

    hipMemsetAsync(d_ws, 0, 1344 * sizeof(float), stream);

    k2_enc12<<<15, 256, 0, stream>>>(x, e1_w, e1_b, bn2_g, bn2_b, e2_w, e2_b, h2, bn3s, bn3q);
    k3_enc3<<<7, 256, 0, stream>>>(h2, bn3_g, bn3_b, bn3s, bn3q, e3_w, e3_b, h3, bn4s, bn4q);
    k4_enc4<<<4, 256, 0, stream>>>(h3, bn4_g, bn4_b, bn4s, bn4q, e4_w, e4_b, h800);
    k5_gemv1<<<8192, 256, 0, stream>>>(efc_w, h800, efc_b, z);
    k67_afpow<<<1, 1024, 0, stream>>>(z, pw);
    k8_gemv2<<<800, 256, 0, stream>>>(dfc_w, z, pw, dfc_b, dvec, dbn4s, dbn4q);
    k9_dec4<<<14, 256, 0, stream>>>(dvec, dbn4_g, dbn4_b, dbn4s, dbn4q, d4_w, d4_b, h4, dbn3s, dbn3q);
    k10_dec3<<<29, 256, 0, stream>>>(h4, dbn3_g, dbn3_b, dbn3s, dbn3q, d3_w, d3_b, h5, dbn2s, dbn2q);
    k11_dec2<<<31, 512, 0, stream>>>(h5, dbn2_g, dbn2_b, dbn2s, dbn2q, d2_w, d2_b, h6, dbn1s, dbn1q);
    k12_dec1<<<1, 512, 0, stream>>>(h6, dbn1_g, dbn1_b, dbn1s, dbn1q, d1_w, d1_b, out);
}

// Round 5
// 506.075 us; speedup vs baseline: 1.2287x; 1.0740x over previous
//
#include <hip/hip_runtime.h>
#include <math.h>

#define EPS 1e-5f

__device__ __forceinline__ float waveReduceSum(float v) {
#pragma unroll
    for (int off = 32; off > 0; off >>= 1) v += __shfl_xor(v, off, 64);
    return v;
}

// ================= generic encoder conv (VALID, k=3), wave-per-output =================
// out[oc][p] = bias[oc] + sum_ic sum_k f(xin[ic][p+k]) * w[oc][ic*3+k]
// f = bn-then-relu (BN_FIRST) or relu-then-bn. Optional stats on out (relu'd or raw).
template <int IC, int OC, int LIN, int LOUT, bool BN_FIRST, bool STATS_RELU>
__global__ __launch_bounds__(256) void enc_conv(const float* __restrict__ xin,
                                                const float* __restrict__ g, const float* __restrict__ bb,
                                                const float* __restrict__ s, const float* __restrict__ q,
                                                const float* __restrict__ w, const float* __restrict__ bias,
                                                float* __restrict__ out,
                                                float* __restrict__ so, float* __restrict__ qo) {
    __shared__ float sc[IC], sh[IC];
    int t = threadIdx.x;
    for (int ic = t; ic < IC; ic += 256) {
        float mean = s[ic] / (float)LIN;
        float var = q[ic] / (float)LIN - mean * mean;
        float scale = g[ic] * rsqrtf(var + EPS);
        sc[ic] = scale; sh[ic] = bb[ic] - mean * scale;
    }
    __syncthreads();
    int o = blockIdx.x * 4 + (t >> 6);
    int lane = t & 63;
    if (o >= OC * LOUT) return;
    int oc = o / LOUT, p = o % LOUT;
    constexpr int TERMS = IC * 3;
    const float* wr = w + oc * TERMS;
    float acc = 0.f;
#pragma unroll
    for (int i = 0; i < (TERMS + 63) / 64; i++) {
        int j = 64 * i + lane;
        if ((TERMS & 63) && j >= TERMS) break;
        int ic = j / 3, k = j - ic * 3;
        float xv = xin[ic * LIN + p + k];
        float v;
        if (BN_FIRST) { v = xv * sc[ic] + sh[ic]; v = v > 0.f ? v : 0.f; }
        else          { xv = xv > 0.f ? xv : 0.f; v = xv * sc[ic] + sh[ic]; }
        acc += v * wr[j];
    }
    acc = waveReduceSum(acc);
    if (lane == 0) {
        acc += bias[oc];
        out[oc * LOUT + p] = acc;
        if (so) {
            float r = STATS_RELU ? (acc > 0.f ? acc : 0.f) : acc;
            atomicAdd(&so[oc], r); atomicAdd(&qo[oc], r * r);
        }
    }
}

// ================= generic convT (k=5, pad=4), wave-per-output =================
// out[oc][p] = bias[oc] + sum_ic sum_kk f(xin[ic][p-kk]) * w[ic][oc*5+kk], 0<=p-kk<LIN
template <int IC, int OC, int LIN, int LOUT, bool BN_FIRST, bool STATS_RELU>
__global__ __launch_bounds__(256) void dec_convt(const float* __restrict__ xin,
                                                 const float* __restrict__ g, const float* __restrict__ bb,
                                                 const float* __restrict__ s, const float* __restrict__ q,
                                                 const float* __restrict__ w, const float* __restrict__ bias,
                                                 float* __restrict__ out,
                                                 float* __restrict__ so, float* __restrict__ qo) {
    __shared__ float sc[IC], sh[IC];
    int t = threadIdx.x;
    for (int ic = t; ic < IC; ic += 256) {
        float mean = s[ic] / (float)LIN;
        float var = q[ic] / (float)LIN - mean * mean;
        float scale = g[ic] * rsqrtf(var + EPS);
        sc[ic] = scale; sh[ic] = bb[ic] - mean * scale;
    }
    __syncthreads();
    int o = blockIdx.x * 4 + (t >> 6);
    int lane = t & 63;
    if (o >= OC * LOUT) return;
    int oc = o / LOUT, p = o % LOUT;
    constexpr int TERMS = IC * 5;
    float acc = 0.f;
#pragma unroll
    for (int i = 0; i < (TERMS + 63) / 64; i++) {
        int j = 64 * i + lane;
        if ((TERMS & 63) && j >= TERMS) break;
        int ic = j / 5, kk = j - ic * 5;
        int m = p - kk;
        if (m >= 0 && m < LIN) {
            float xv = xin[ic * LIN + m];
            float v;
            if (BN_FIRST) { v = xv * sc[ic] + sh[ic]; v = v > 0.f ? v : 0.f; }
            else          { xv = xv > 0.f ? xv : 0.f; v = xv * sc[ic] + sh[ic]; }
            acc += v * w[ic * (OC * 5) + oc * 5 + kk];
        }
    }
    acc = waveReduceSum(acc);
    if (lane == 0) {
        acc += bias[oc];
        out[oc * LOUT + p] = acc;
        if (so) {
            float r = STATS_RELU ? (acc > 0.f ? acc : 0.f) : acc;
            atomicAdd(&so[oc], r); atomicAdd(&qo[oc], r * r);
        }
    }
}

// ================= K2: e1(1->256,k3)+bn2+relu recompute + e2(256->128,k3) + bn3 stats =================
// wave-per-output; e1 conv recomputed on the fly from LDS copies of x, e1_w, e1_b
__global__ __launch_bounds__(256) void k2_enc12(const float* __restrict__ x,
                                                const float* __restrict__ w1,
                                                const float* __restrict__ b1,
                                                const float* __restrict__ g2,
                                                const float* __restrict__ bb2,
                                                const float* __restrict__ w2,
                                                const float* __restrict__ b2,
                                                float* __restrict__ h2,
                                                float* __restrict__ s3, float* __restrict__ q3) {
    __shared__ float xs[33];
    __shared__ float w1l[768];
    __shared__ float b1l[256];
    __shared__ float sc2[256], sh2[256];
    int t = threadIdx.x;
    if (t < 33) xs[t] = x[t];
    for (int i = t; i < 768; i += 256) w1l[i] = w1[i];
    b1l[t] = b1[t];
    __syncthreads();
    {   // thread t: bn2 stats for channel t
        float w0 = w1l[t * 3], wa = w1l[t * 3 + 1], wb = w1l[t * 3 + 2], bias = b1l[t];
        float s = 0.f, q = 0.f;
#pragma unroll
        for (int pp = 0; pp < 31; pp++) {
            float v = xs[pp] * w0 + xs[pp + 1] * wa + xs[pp + 2] * wb + bias;
            s += v; q += v * v;
        }
        float mean = s / 31.f;
        float var = q / 31.f - mean * mean;
        float scale = g2[t] * rsqrtf(var + EPS);
        sc2[t] = scale; sh2[t] = bb2[t] - mean * scale;
    }
    __syncthreads();
    int o = blockIdx.x * 4 + (t >> 6);   // 3712 outputs
    int lane = t & 63;
    int oc = o / 29, p = o % 29;
    const float* wr = w2 + oc * 768;
    float acc = 0.f;
#pragma unroll
    for (int i = 0; i < 12; i++) {
        int j = 64 * i + lane;
        int ic = j / 3, k = j - ic * 3;
        int pos = p + k;
        float e1v = xs[pos] * w1l[ic * 3] + xs[pos + 1] * w1l[ic * 3 + 1] + xs[pos + 2] * w1l[ic * 3 + 2] + b1l[ic];
        float v = e1v * sc2[ic] + sh2[ic];
        v = v > 0.f ? v : 0.f;
        acc += v * wr[j];
    }
    acc = waveReduceSum(acc);
    if (lane == 0) {
        acc += b2[oc];
        h2[oc * 29 + p] = acc;
        atomicAdd(&s3[oc], acc);
        atomicAdd(&q3[oc], acc * acc);
    }
}

// ================= K5: z = efc_w @ h800 + efc_b (32768 x 800) =================
__global__ __launch_bounds__(256) void k5_gemv1(const float* __restrict__ w,
                                                const float* __restrict__ h,
                                                const float* __restrict__ b,
                                                float* __restrict__ z) {
    int wave = threadIdx.x >> 6;
    int lane = threadIdx.x & 63;
    int row = blockIdx.x * 4 + wave;
    const float4* wr = (const float4*)(w + (size_t)row * 800);
    const float4* hv = (const float4*)h;
    float acc = 0.f;
#pragma unroll
    for (int t = 0; t < 3; t++) {
        float4 a = wr[lane + 64 * t];
        float4 c = hv[lane + 64 * t];
        acc += a.x * c.x + a.y * c.y + a.z * c.z + a.w * c.w;
    }
    if (lane < 8) {
        float4 a = wr[192 + lane];
        float4 c = hv[192 + lane];
        acc += a.x * c.x + a.y * c.y + a.z * c.z + a.w * c.w;
    }
    acc = waveReduceSum(acc);
    if (lane == 0) z[row] = acc + b[row];
}

// ================= K67: Af + powers =================
__global__ __launch_bounds__(1024) void k67_afpow(const float* __restrict__ z, float* __restrict__ pw) {
    int t = threadIdx.x;
    const float4* z4 = (const float4*)z;
    float xy = 0.f, xx = 0.f;
    for (int v = t; v < 8191; v += 1024) {
        float4 a = z4[v];
        float nb = z[4 * v + 4];
        xy += a.x * a.y + a.y * a.z + a.z * a.w + a.w * nb;
        xx += a.x * a.x + a.y * a.y + a.z * a.z + a.w * a.w;
    }
    if (t < 3) {
        int i = 32764 + t;
        xy += z[i] * z[i + 1];
        xx += z[i] * z[i];
    }
    xy = waveReduceSum(xy);
    xx = waveReduceSum(xx);
    __shared__ float sx[16], sy[16];
    __shared__ float afs;
    int wv = t >> 6, ln = t & 63;
    if (ln == 0) { sy[wv] = xy; sx[wv] = xx; }
    __syncthreads();
    if (t == 0) {
        float SY = 0.f, SX = 0.f;
        for (int i = 0; i < 16; i++) { SY += sy[i]; SX += sx[i]; }
        afs = SY / (SX + 0.01f);
    }
    __syncthreads();
    float base0 = afs;
    float4* pw4 = (float4*)pw;
    for (int v = t; v < 8192; v += 1024) {
        float4 r;
        float* rp = (float*)&r;
#pragma unroll
        for (int u = 0; u < 4; u++) {
            int e = 4 * v + u;
            float rr = 1.f, base = base0;
            while (e) { if (e & 1) rr *= base; base *= base; e >>= 1; }
            rp[u] = rr;
        }
        pw4[v] = r;
    }
}

// ================= K8: d(2x800) = out2 @ dfc_w.T + dfc_b, + dbn4 stats =================
__global__ __launch_bounds__(256) void k8_gemv2(const float* __restrict__ w,
                                                const float* __restrict__ z,
                                                const float* __restrict__ pw,
                                                const float* __restrict__ b,
                                                float* __restrict__ d,
                                                float* __restrict__ s, float* __restrict__ q) {
    int j = blockIdx.x;  // 0..799
    int t = threadIdx.x;
    const float* wr = w + (size_t)j * 32767;
    int head = j & 3;     // aligns row to 16B
    float a0 = 0.f, a1 = 0.f;
    if (t < head) { float wv = wr[t]; a0 += z[t] * wv; a1 += pw[t] * wv; }
    int n4 = (32767 - head) >> 2;
    const float4* wv4 = (const float4*)(wr + head);
    for (int v = t; v < n4; v += 256) {
        float4 a = wv4[v];
        int i = head + 4 * v;
        a0 += z[i] * a.x + z[i + 1] * a.y + z[i + 2] * a.z + z[i + 3] * a.w;
        a1 += pw[i] * a.x + pw[i + 1] * a.y + pw[i + 2] * a.z + pw[i + 3] * a.w;
    }
    int tail = (32767 - head) & 3;
    int tstart = head + 4 * n4;
    if (t < tail) { int i = tstart + t; float wv = wr[i]; a0 += z[i] * wv; a1 += pw[i] * wv; }

    a0 = waveReduceSum(a0);
    a1 = waveReduceSum(a1);
    __shared__ float r0[4], r1[4];
    int wave = t >> 6, lane = t & 63;
    if (lane == 0) { r0[wave] = a0; r1[wave] = a1; }
    __syncthreads();
    if (t == 0) {
        float d0 = r0[0] + r0[1] + r0[2] + r0[3] + b[j];
        float d1 = z[0] * (r1[0] + r1[1] + r1[2] + r1[3]) + b[j];
        d[j] = d0;
        d[800 + j] = d1;
        int c0 = j / 50, c1 = 16 + j / 50;
        atomicAdd(&s[c0], d0); atomicAdd(&q[c0], d0 * d0);
        atomicAdd(&s[c1], d1); atomicAdd(&q[c1], d1 * d1);
    }
}

// ================= K12: dbn1+relu + convT d1 (256->1,k3) -> out(64), wave-per-output =================
__global__ __launch_bounds__(256) void k12_dec1(const float* __restrict__ h6,
                                                const float* __restrict__ g, const float* __restrict__ bb,
                                                const float* __restrict__ s, const float* __restrict__ q,
                                                const float* __restrict__ w, const float* __restrict__ b1,
                                                float* __restrict__ out) {
    __shared__ float sc[256], sh[256];
    int t = threadIdx.x;
    {
        float mean = s[t] / 62.f;
        float var = q[t] / 62.f - mean * mean;
        float scale = g[t] * rsqrtf(var + EPS);
        sc[t] = scale; sh[t] = bb[t] - mean * scale;
    }
    __syncthreads();
    int p = blockIdx.x * 4 + (t >> 6);   // 64 outputs
    int lane = t & 63;
    float acc = 0.f;
#pragma unroll
    for (int i = 0; i < 12; i++) {
        int j = 64 * i + lane;
        int ic = j / 3, kk = j - ic * 3;
        int m = p - kk;
        if (m >= 0 && m < 62) {
            float v = h6[ic * 62 + m] * sc[ic] + sh[ic];
            v = v > 0.f ? v : 0.f;   // bn then relu
            acc += v * w[j];
        }
    }
    acc = waveReduceSum(acc);
    if (lane == 0) out[p] = acc + b1[0];
}

// ================= launcher =================
extern "C" void kernel_launch(void* const* d_in, const int* in_sizes, int n_in,
                              void* d_out, int out_size, void* d_ws, size_t ws_size,
                              hipStream_t stream) {
    const float* x      = (const float*)d_in[0];
    const float* e1_w   = (const float*)d_in[1];
    const float* e1_b   = (const float*)d_in[2];
    const float* bn2_g  = (const float*)d_in[3];
    const float* bn2_b  = (const float*)d_in[4];
    const float* e2_w   = (const float*)d_in[5];
    const float* e2_b   = (const float*)d_in[6];
    const float* bn3_g  = (const float*)d_in[7];
    const float* bn3_b  = (const float*)d_in[8];
    const float* e3_w   = (const float*)d_in[9];
    const float* e3_b   = (const float*)d_in[10];
    const float* bn4_g  = (const float*)d_in[11];
    const float* bn4_b  = (const float*)d_in[12];
    const float* e4_w   = (const float*)d_in[13];
    const float* e4_b   = (const float*)d_in[14];
    const float* efc_w  = (const float*)d_in[15];
    const float* efc_b  = (const float*)d_in[16];
    const float* dfc_w  = (const float*)d_in[17];
    const float* dfc_b  = (const float*)d_in[18];
    const float* dbn4_g = (const float*)d_in[19];
    const float* dbn4_b = (const float*)d_in[20];
    const float* d4_w   = (const float*)d_in[21];
    const float* d4_b   = (const float*)d_in[22];
    const float* dbn3_g = (const float*)d_in[23];
    const float* dbn3_b = (const float*)d_in[24];
    const float* d3_w   = (const float*)d_in[25];
    const float* d3_b   = (const float*)d_in[26];
    const float* dbn2_g = (const float*)d_in[27];
    const float* dbn2_b = (const float*)d_in[28];
    const float* d2_w   = (const float*)d_in[29];
    const float* d2_b   = (const float*)d_in[30];
    const float* dbn1_g = (const float*)d_in[31];
    const float* dbn1_b = (const float*)d_in[32];
    const float* d1_w   = (const float*)d_in[33];
    const float* d1_b   = (const float*)d_in[34];
    float* out = (float*)d_out;

    float* W = (float*)d_ws;
    float* bn3s  = W + 0;    float* bn3q  = W + 128;
    float* bn4s  = W + 256;  float* bn4q  = W + 320;
    float* dbn4s = W + 384;  float* dbn4q = W + 416;
    float* dbn3s = W + 448;  float* dbn3q = W + 512;
    float* dbn2s = W + 576;  float* dbn2q = W + 704;
    float* dbn1s = W + 832;  float* dbn1q = W + 1088;   // stats end at 1344
    float* h2    = W + 1344;   // 128*29
    float* h3    = W + 5056;   // 64*27
    float* h800  = W + 6784;   // 800 (16B aligned)
    float* z     = W + 7584;   // 32768 (16B aligned)
    float* pw    = W + 40352;  // 32768 (16B aligned)
    float* dvec  = W + 73120;  // 1600
    float* h4    = W + 74720;  // 64*54
    float* h5    = W + 78176;  // 128*58
    float* h6    = W + 85600;  // 256*62

    hipMemsetAsync(d_ws, 0, 1344 * sizeof(float), stream);

    // encoder
    k2_enc12<<<928, 256, 0, stream>>>(x, e1_w, e1_b, bn2_g, bn2_b, e2_w, e2_b, h2, bn3s, bn3q);
    // h2 -> bn3(bn-first)+relu -> e3 conv -> h3, bn4 stats on relu(h3)
    enc_conv<128, 64, 29, 27, true, true><<<432, 256, 0, stream>>>(
        h2, bn3_g, bn3_b, bn3s, bn3q, e3_w, e3_b, h3, bn4s, bn4q);
    // h3 -> relu-first then bn4 -> e4 conv -> h800, no stats
    enc_conv<64, 32, 27, 25, false, false><<<200, 256, 0, stream>>>(
        h3, bn4_g, bn4_b, bn4s, bn4q, e4_w, e4_b, h800, nullptr, nullptr);
    // FC encoder
    k5_gemv1<<<8192, 256, 0, stream>>>(efc_w, h800, efc_b, z);
    k67_afpow<<<1, 1024, 0, stream>>>(z, pw);
    k8_gemv2<<<800, 256, 0, stream>>>(dfc_w, z, pw, dfc_b, dvec, dbn4s, dbn4q);
    // decoder
    // dvec -> dbn4(bn-first)+relu -> convT d4 -> h4, dbn3 stats on relu(h4)
    dec_convt<32, 64, 50, 54, true, true><<<864, 256, 0, stream>>>(
        dvec, dbn4_g, dbn4_b, dbn4s, dbn4q, d4_w, d4_b, h4, dbn3s, dbn3q);
    // h4 -> relu then dbn3 -> convT d3 -> h5, dbn2 stats on relu(h5)
    dec_convt<64, 128, 54, 58, false, true><<<1856, 256, 0, stream>>>(
        h4, dbn3_g, dbn3_b, dbn3s, dbn3q, d3_w, d3_b, h5, dbn2s, dbn2q);
    // h5 -> relu then dbn2 -> convT d2 -> h6, dbn1 stats on raw h6
    dec_convt<128, 256, 58, 62, false, false><<<3968, 256, 0, stream>>>(
        h5, dbn2_g, dbn2_b, dbn2s, dbn2q, d2_w, d2_b, h6, dbn1s, dbn1q);
    // h6 -> dbn1(bn-first)+relu -> convT d1 -> out(64)
    k12_dec1<<<16, 256, 0, stream>>>(h6, dbn1_g, dbn1_b, dbn1s, dbn1q, d1_w, d1_b, out);
}

// Round 10
// 420.113 us; speedup vs baseline: 1.4802x; 1.2046x over previous
//
#include <hip/hip_runtime.h>
#include <math.h>

#define EPS 1e-5f

__device__ __forceinline__ float waveReduceSum(float v) {
#pragma unroll
    for (int off = 32; off > 0; off >>= 1) v += __shfl_xor(v, off, 64);
    return v;
}

// ================= encoder conv (VALID, k=3): wave-per-oc, lane-per-p =================
// out[oc][p] = bias[oc] + sum_ic sum_k f(xin[ic][p+k]) * w[oc][ic*3+k]
// Weights are wave-uniform (1 line broadcast); x staged in LDS with BN applied.
template <int IC, int OC, int LIN, bool BN_FIRST, bool HAS_STATS, bool STATS_RELU>
__global__ __launch_bounds__(256) void enc_conv2(const float* __restrict__ xin,
                                                 const float* __restrict__ g, const float* __restrict__ bb,
                                                 const float* __restrict__ s, const float* __restrict__ q,
                                                 const float* __restrict__ w, const float* __restrict__ bias,
                                                 float* __restrict__ out,
                                                 float* __restrict__ so, float* __restrict__ qo) {
    constexpr int LOUT = LIN - 2;
    __shared__ float sc[IC], sh[IC];
    __shared__ float xn[IC * LIN];
    int t = threadIdx.x;
    for (int ic = t; ic < IC; ic += 256) {
        float mean = s[ic] / (float)LIN;
        float var = q[ic] / (float)LIN - mean * mean;
        float scale = g[ic] * rsqrtf(var + EPS);
        sc[ic] = scale; sh[ic] = bb[ic] - mean * scale;
    }
    __syncthreads();
    for (int i = t; i < IC * LIN; i += 256) {
        int ic = i / LIN;
        float xv = xin[i];
        float v;
        if (BN_FIRST) { v = xv * sc[ic] + sh[ic]; v = fmaxf(v, 0.f); }
        else          { xv = fmaxf(xv, 0.f); v = xv * sc[ic] + sh[ic]; }
        xn[i] = v;
    }
    __syncthreads();
    int oc = blockIdx.x * 4 + (t >> 6);
    int p0 = t & 63;
    int p = p0 < LOUT ? p0 : 0;          // clamp invalid lanes to a safe index
    const float* woc = w + oc * (IC * 3);
    float acc = 0.f;
#pragma unroll 8
    for (int ic = 0; ic < IC; ic++) {
        const float* xi = xn + ic * LIN;
        const float* wi = woc + ic * 3;   // wave-uniform address -> broadcast
        acc += xi[p] * wi[0] + xi[p + 1] * wi[1] + xi[p + 2] * wi[2];
    }
    float val = acc + bias[oc];
    if constexpr (HAS_STATS) {
        float r = (p0 < LOUT) ? (STATS_RELU ? fmaxf(val, 0.f) : val) : 0.f;
        float ssum = waveReduceSum(r);
        float qsum = waveReduceSum(r * r);
        if (p0 == 0) { so[oc] = ssum; qo[oc] = qsum; }   // single producer: plain store
    }
    if (p0 < LOUT) out[oc * LOUT + p0] = val;
}

// ================= convT (k=5, pad=4): wave-per-oc, lane-per-p =================
// out[oc][p] = bias[oc] + sum_ic sum_kk f(xin[ic][p-kk]) * w[ic][oc*5+kk], 0<=p-kk<LIN
template <int IC, int OC, int LIN, bool BN_FIRST, bool HAS_STATS, bool STATS_RELU>
__global__ __launch_bounds__(256) void dec_convt2(const float* __restrict__ xin,
                                                  const float* __restrict__ g, const float* __restrict__ bb,
                                                  const float* __restrict__ s, const float* __restrict__ q,
                                                  const float* __restrict__ w, const float* __restrict__ bias,
                                                  float* __restrict__ out,
                                                  float* __restrict__ so, float* __restrict__ qo) {
    constexpr int LOUT = LIN + 4;
    __shared__ float sc[IC], sh[IC];
    __shared__ float xn[IC * LIN];
    int t = threadIdx.x;
    for (int ic = t; ic < IC; ic += 256) {
        float mean = s[ic] / (float)LIN;
        float var = q[ic] / (float)LIN - mean * mean;
        float scale = g[ic] * rsqrtf(var + EPS);
        sc[ic] = scale; sh[ic] = bb[ic] - mean * scale;
    }
    __syncthreads();
    for (int i = t; i < IC * LIN; i += 256) {
        int ic = i / LIN;
        float xv = xin[i];
        float v;
        if (BN_FIRST) { v = xv * sc[ic] + sh[ic]; v = fmaxf(v, 0.f); }
        else          { xv = fmaxf(xv, 0.f); v = xv * sc[ic] + sh[ic]; }
        xn[i] = v;
    }
    __syncthreads();
    int oc = blockIdx.x * 4 + (t >> 6);
    int p = t & 63;                       // m-guard naturally zeroes lanes p>=LOUT
    const float* woc = w + oc * 5;
    float acc = 0.f;
#pragma unroll 8
    for (int ic = 0; ic < IC; ic++) {
        const float* wi = woc + ic * (OC * 5);   // wave-uniform -> broadcast
        const float* xi = xn + ic * LIN;
#pragma unroll
        for (int kk = 0; kk < 5; kk++) {
            int m = p - kk;
            float xv = (m >= 0 && m < LIN) ? xi[m] : 0.f;
            acc += xv * wi[kk];
        }
    }
    float val = acc + bias[oc];
    if constexpr (HAS_STATS) {
        float r = (p < LOUT) ? (STATS_RELU ? fmaxf(val, 0.f) : val) : 0.f;
        float ssum = waveReduceSum(r);
        float qsum = waveReduceSum(r * r);
        if (p == 0) { so[oc] = ssum; qo[oc] = qsum; }
    }
    if (p < LOUT) out[oc * LOUT + p] = val;
}

// ================= K2: e1(1->256,k3)+bn2+relu staged in LDS + e2(256->128,k3), wave-per-oc =================
__global__ __launch_bounds__(256) void k2_enc12(const float* __restrict__ x,
                                                const float* __restrict__ w1,
                                                const float* __restrict__ b1,
                                                const float* __restrict__ g2,
                                                const float* __restrict__ bb2,
                                                const float* __restrict__ w2,
                                                const float* __restrict__ b2,
                                                float* __restrict__ h2,
                                                float* __restrict__ s3, float* __restrict__ q3) {
    __shared__ float xs[33];
    __shared__ float e1n[256 * 33];   // stride 33: conflict-free row writes + lane reads
    int t = threadIdx.x;
    if (t < 33) xs[t] = x[t];
    __syncthreads();
    {   // thread t = e1 channel t: conv + bn2 stats + bn2 + relu -> LDS row
        float w0 = w1[t * 3], wa = w1[t * 3 + 1], wb = w1[t * 3 + 2], bias = b1[t];
        float vals[31];
        float s = 0.f, q = 0.f;
#pragma unroll
        for (int pp = 0; pp < 31; pp++) {
            float v = xs[pp] * w0 + xs[pp + 1] * wa + xs[pp + 2] * wb + bias;
            vals[pp] = v; s += v; q += v * v;
        }
        float mean = s / 31.f;
        float var = q / 31.f - mean * mean;
        float scale = g2[t] * rsqrtf(var + EPS);
        float shift = bb2[t] - mean * scale;
#pragma unroll
        for (int pp = 0; pp < 31; pp++) {
            float v = vals[pp] * scale + shift;
            e1n[t * 33 + pp] = fmaxf(v, 0.f);
        }
    }
    __syncthreads();
    int oc = blockIdx.x * 4 + (t >> 6);   // 128 ocs, 32 blocks
    int p0 = t & 63;
    int p = p0 < 29 ? p0 : 0;
    const float* woc = w2 + oc * 768;
    float acc = 0.f;
#pragma unroll 8
    for (int ic = 0; ic < 256; ic++) {
        const float* xi = e1n + ic * 33;
        const float* wi = woc + ic * 3;   // wave-uniform
        acc += xi[p] * wi[0] + xi[p + 1] * wi[1] + xi[p + 2] * wi[2];
    }
    float val = acc + b2[oc];
    float r = (p0 < 29) ? val : 0.f;      // bn3 stats on raw h2
    float ssum = waveReduceSum(r);
    float qsum = waveReduceSum(r * r);
    if (p0 == 0) { s3[oc] = ssum; q3[oc] = qsum; }
    if (p0 < 29) h2[oc * 29 + p0] = val;
}

// ================= K5: z = efc_w @ h800 + efc_b (32768 x 800) =================
__global__ __launch_bounds__(256) void k5_gemv1(const float* __restrict__ w,
                                                const float* __restrict__ h,
                                                const float* __restrict__ b,
                                                float* __restrict__ z) {
    int wave = threadIdx.x >> 6;
    int lane = threadIdx.x & 63;
    int row = blockIdx.x * 4 + wave;
    const float4* wr = (const float4*)(w + (size_t)row * 800);
    const float4* hv = (const float4*)h;
    float acc = 0.f;
#pragma unroll
    for (int t = 0; t < 3; t++) {
        float4 a = wr[lane + 64 * t];
        float4 c = hv[lane + 64 * t];
        acc += a.x * c.x + a.y * c.y + a.z * c.z + a.w * c.w;
    }
    if (lane < 8) {
        float4 a = wr[192 + lane];
        float4 c = hv[192 + lane];
        acc += a.x * c.x + a.y * c.y + a.z * c.z + a.w * c.w;
    }
    acc = waveReduceSum(acc);
    if (lane == 0) z[row] = acc + b[row];
}

// ================= K67: Af + powers =================
__global__ __launch_bounds__(1024) void k67_afpow(const float* __restrict__ z, float* __restrict__ pw) {
    int t = threadIdx.x;
    const float4* z4 = (const float4*)z;
    float xy = 0.f, xx = 0.f;
    for (int v = t; v < 8191; v += 1024) {
        float4 a = z4[v];
        float nb = z[4 * v + 4];
        xy += a.x * a.y + a.y * a.z + a.z * a.w + a.w * nb;
        xx += a.x * a.x + a.y * a.y + a.z * a.z + a.w * a.w;
    }
    if (t < 3) {
        int i = 32764 + t;
        xy += z[i] * z[i + 1];
        xx += z[i] * z[i];
    }
    xy = waveReduceSum(xy);
    xx = waveReduceSum(xx);
    __shared__ float sx[16], sy[16];
    __shared__ float afs;
    int wv = t >> 6, ln = t & 63;
    if (ln == 0) { sy[wv] = xy; sx[wv] = xx; }
    __syncthreads();
    if (t == 0) {
        float SY = 0.f, SX = 0.f;
        for (int i = 0; i < 16; i++) { SY += sy[i]; SX += sx[i]; }
        afs = SY / (SX + 0.01f);
    }
    __syncthreads();
    float base0 = afs;
    float4* pw4 = (float4*)pw;
    for (int v = t; v < 8192; v += 1024) {
        float4 r;
        float* rp = (float*)&r;
#pragma unroll
        for (int u = 0; u < 4; u++) {
            int e = 4 * v + u;
            float rr = 1.f, base = base0;
            while (e) { if (e & 1) rr *= base; base *= base; e >>= 1; }
            rp[u] = rr;
        }
        pw4[v] = r;
    }
}

// ================= K8: d(2x800) = out2 @ dfc_w.T + dfc_b, + dbn4 stats =================
__global__ __launch_bounds__(256) void k8_gemv2(const float* __restrict__ w,
                                                const float* __restrict__ z,
                                                const float* __restrict__ pw,
                                                const float* __restrict__ b,
                                                float* __restrict__ d,
                                                float* __restrict__ s, float* __restrict__ q) {
    int j = blockIdx.x;  // 0..799
    int t = threadIdx.x;
    const float* wr = w + (size_t)j * 32767;
    int head = j & 3;     // aligns row to 16B
    float a0 = 0.f, a1 = 0.f;
    if (t < head) { float wv = wr[t]; a0 += z[t] * wv; a1 += pw[t] * wv; }
    int n4 = (32767 - head) >> 2;
    const float4* wv4 = (const float4*)(wr + head);
    for (int v = t; v < n4; v += 256) {
        float4 a = wv4[v];
        int i = head + 4 * v;
        a0 += z[i] * a.x + z[i + 1] * a.y + z[i + 2] * a.z + z[i + 3] * a.w;
        a1 += pw[i] * a.x + pw[i + 1] * a.y + pw[i + 2] * a.z + pw[i + 3] * a.w;
    }
    int tail = (32767 - head) & 3;
    int tstart = head + 4 * n4;
    if (t < tail) { int i = tstart + t; float wv = wr[i]; a0 += z[i] * wv; a1 += pw[i] * wv; }

    a0 = waveReduceSum(a0);
    a1 = waveReduceSum(a1);
    __shared__ float r0[4], r1[4];
    int wave = t >> 6, lane = t & 63;
    if (lane == 0) { r0[wave] = a0; r1[wave] = a1; }
    __syncthreads();
    if (t == 0) {
        float d0 = r0[0] + r0[1] + r0[2] + r0[3] + b[j];
        float d1 = z[0] * (r1[0] + r1[1] + r1[2] + r1[3]) + b[j];
        d[j] = d0;
        d[800 + j] = d1;
        int c0 = j / 50, c1 = 16 + j / 50;
        atomicAdd(&s[c0], d0); atomicAdd(&q[c0], d0 * d0);
        atomicAdd(&s[c1], d1); atomicAdd(&q[c1], d1 * d1);
    }
}

// ================= K12: dbn1+relu + convT d1 (256->1,k3) -> out(64), wave-per-output =================
__global__ __launch_bounds__(256) void k12_dec1(const float* __restrict__ h6,
                                                const float* __restrict__ g, const float* __restrict__ bb,
                                                const float* __restrict__ s, const float* __restrict__ q,
                                                const float* __restrict__ w, const float* __restrict__ b1,
                                                float* __restrict__ out) {
    __shared__ float sc[256], sh[256];
    int t = threadIdx.x;
    {
        float mean = s[t] / 62.f;
        float var = q[t] / 62.f - mean * mean;
        float scale = g[t] * rsqrtf(var + EPS);
        sc[t] = scale; sh[t] = bb[t] - mean * scale;
    }
    __syncthreads();
    int p = blockIdx.x * 4 + (t >> 6);   // 64 outputs
    int lane = t & 63;
    float acc = 0.f;
#pragma unroll
    for (int i = 0; i < 12; i++) {
        int j = 64 * i + lane;
        int ic = j / 3, kk = j - ic * 3;
        int m = p - kk;
        if (m >= 0 && m < 62) {
            float v = h6[ic * 62 + m] * sc[ic] + sh[ic];
            v = fmaxf(v, 0.f);   // bn then relu
            acc += v * w[j];
        }
    }
    acc = waveReduceSum(acc);
    if (lane == 0) out[p] = acc + b1[0];
}

// ================= launcher =================
extern "C" void kernel_launch(void* const* d_in, const int* in_sizes, int n_in,
                              void* d_out, int out_size, void* d_ws, size_t ws_size,
                              hipStream_t stream) {
    const float* x      = (const float*)d_in[0];
    const float* e1_w   = (const float*)d_in[1];
    const float* e1_b   = (const float*)d_in[2];
    const float* bn2_g  = (const float*)d_in[3];
    const float* bn2_b  = (const float*)d_in[4];
    const float* e2_w   = (const float*)d_in[5];
    const float* e2_b   = (const float*)d_in[6];
    const float* bn3_g  = (const float*)d_in[7];
    const float* bn3_b  = (const float*)d_in[8];
    const float* e3_w   = (const float*)d_in[9];
    const float* e3_b   = (const float*)d_in[10];
    const float* bn4_g  = (const float*)d_in[11];
    const float* bn4_b  = (const float*)d_in[12];
    const float* e4_w   = (const float*)d_in[13];
    const float* e4_b   = (const float*)d_in[14];
    const float* efc_w  = (const float*)d_in[15];
    const float* efc_b  = (const float*)d_in[16];
    const float* dfc_w  = (const float*)d_in[17];
    const float* dfc_b  = (const float*)d_in[18];
    const float* dbn4_g = (const float*)d_in[19];
    const float* dbn4_b = (const float*)d_in[20];
    const float* d4_w   = (const float*)d_in[21];
    const float* d4_b   = (const float*)d_in[22];
    const float* dbn3_g = (const float*)d_in[23];
    const float* dbn3_b = (const float*)d_in[24];
    const float* d3_w   = (const float*)d_in[25];
    const float* d3_b   = (const float*)d_in[26];
    const float* dbn2_g = (const float*)d_in[27];
    const float* dbn2_b = (const float*)d_in[28];
    const float* d2_w   = (const float*)d_in[29];
    const float* d2_b   = (const float*)d_in[30];
    const float* dbn1_g = (const float*)d_in[31];
    const float* dbn1_b = (const float*)d_in[32];
    const float* d1_w   = (const float*)d_in[33];
    const float* d1_b   = (const float*)d_in[34];
    float* out = (float*)d_out;

    float* W = (float*)d_ws;
    float* bn3s  = W + 0;    float* bn3q  = W + 128;
    float* bn4s  = W + 256;  float* bn4q  = W + 320;
    float* dbn4s = W + 384;  float* dbn4q = W + 416;
    float* dbn3s = W + 448;  float* dbn3q = W + 512;
    float* dbn2s = W + 576;  float* dbn2q = W + 704;
    float* dbn1s = W + 832;  float* dbn1q = W + 1088;   // stats end at 1344
    float* h2    = W + 1344;   // 128*29
    float* h3    = W + 5056;   // 64*27
    float* h800  = W + 6784;   // 800 (16B aligned)
    float* z     = W + 7584;   // 32768 (16B aligned)
    float* pw    = W + 40352;  // 32768 (16B aligned)
    float* dvec  = W + 73120;  // 1600
    float* h4    = W + 74720;  // 64*54
    float* h5    = W + 78176;  // 128*58
    float* h6    = W + 85600;  // 256*62

    // zero the BN-stats accumulators (k8's atomics need it)
    hipMemsetAsync(d_ws, 0, 1344 * sizeof(float), stream);

    // encoder
    k2_enc12<<<32, 256, 0, stream>>>(x, e1_w, e1_b, bn2_g, bn2_b, e2_w, e2_b, h2, bn3s, bn3q);
    // h2 -> bn3(bn-first)+relu -> e3 conv -> h3, bn4 stats on relu(h3)
    enc_conv2<128, 64, 29, true, true, true><<<16, 256, 0, stream>>>(
        h2, bn3_g, bn3_b, bn3s, bn3q, e3_w, e3_b, h3, bn4s, bn4q);
    // h3 -> relu-first then bn4 -> e4 conv -> h800, no stats
    enc_conv2<64, 32, 27, false, false, false><<<8, 256, 0, stream>>>(
        h3, bn4_g, bn4_b, bn4s, bn4q, e4_w, e4_b, h800, nullptr, nullptr);
    // FC encoder
    k5_gemv1<<<8192, 256, 0, stream>>>(efc_w, h800, efc_b, z);
    k67_afpow<<<1, 1024, 0, stream>>>(z, pw);
    k8_gemv2<<<800, 256, 0, stream>>>(dfc_w, z, pw, dfc_b, dvec, dbn4s, dbn4q);
    // decoder
    // dvec -> dbn4(bn-first)+relu -> convT d4 -> h4, dbn3 stats on relu(h4)
    dec_convt2<32, 64, 50, true, true, true><<<16, 256, 0, stream>>>(
        dvec, dbn4_g, dbn4_b, dbn4s, dbn4q, d4_w, d4_b, h4, dbn3s, dbn3q);
    // h4 -> relu then dbn3 -> convT d3 -> h5, dbn2 stats on relu(h5)
    dec_convt2<64, 128, 54, false, true, true><<<32, 256, 0, stream>>>(
        h4, dbn3_g, dbn3_b, dbn3s, dbn3q, d3_w, d3_b, h5, dbn2s, dbn2q);
    // h5 -> relu then dbn2 -> convT d2 -> h6, dbn1 stats on raw h6
    dec_convt2<128, 256, 58, false, true, false><<<64, 256, 0, stream>>>(
        h5, dbn2_g, dbn2_b, dbn2s, dbn2q, d2_w, d2_b, h6, dbn1s, dbn1q);
    // h6 -> dbn1(bn-first)+relu -> convT d1 -> out(64)
    k12_dec1<<<16, 256, 0, stream>>>(h6, dbn1_g, dbn1_b, dbn1s, dbn1q, d1_w, d1_b, out);
}